// Round 10
// baseline (303.835 us; speedup 1.0000x reference)
//
#include <hip/hip_runtime.h>
#include <hip/hip_bf16.h>

typedef __attribute__((ext_vector_type(8))) short s16x8;
typedef __attribute__((ext_vector_type(4))) short s16x4;
typedef __attribute__((ext_vector_type(2))) short s16x2;
typedef __attribute__((ext_vector_type(4))) float f32x4;
typedef __attribute__((ext_vector_type(4))) unsigned int u32x4;

#define L_ 2048
#define HID 2048
#define DH 64

__device__ __forceinline__ short f2bs(float f) {
    __hip_bfloat16 h = __float2bfloat16(f);
    return *reinterpret_cast<short*>(&h);
}
// fast bf16x2 pack: round-half-up + v_perm_b32. a -> low16, b -> high16.
__device__ __forceinline__ unsigned int pkbf_fast(float a, float b) {
    unsigned ua = __builtin_bit_cast(unsigned, a) + 0x8000u;
    unsigned ub = __builtin_bit_cast(unsigned, b) + 0x8000u;
    return __builtin_amdgcn_perm(ub, ua, 0x07060302u);
}
__device__ __forceinline__ float bpermf(int byteidx, float v) {
    int r = __builtin_amdgcn_ds_bpermute(byteidx, __builtin_bit_cast(int, v));
    return __builtin_bit_cast(float, r);
}
// dual-register lane-block swaps (VALU cross-lane, not DS pipe):
// pl_swap32: a' = {a.lanes0-31, b.lanes0-31}, b' = {a.lanes32-63, b.lanes32-63}
__device__ __forceinline__ void pl_swap32(unsigned &a, unsigned &b) {
    asm volatile("v_permlane32_swap_b32 %0, %1" : "+v"(a), "+v"(b));
}
// pl_swap16: a' = {a.q0, b.q0, a.q2, b.q2}, b' = {a.q1, b.q1, a.q3, b.q3}
__device__ __forceinline__ void pl_swap16(unsigned &a, unsigned &b) {
    asm volatile("v_permlane16_swap_b32 %0, %1" : "+v"(a), "+v"(b));
}
__device__ __forceinline__ s16x4 load4_bf16(const float* p) {
    const float4 v = *(const float4*)p;
    s16x4 r; r.x = f2bs(v.x); r.y = f2bs(v.y); r.z = f2bs(v.z); r.w = f2bs(v.w);
    return r;
}
__device__ __forceinline__ s16x4 load4_bf16(const __hip_bfloat16* p) {
    return *(const s16x4*)p;
}
__device__ __forceinline__ void store1(float* p, float v) { *p = v; }
__device__ __forceinline__ void store1(__hip_bfloat16* p, float v) { *p = __float2bfloat16(v); }

__device__ __forceinline__ void glds16(const __hip_bfloat16* g, __hip_bfloat16* l) {
    __builtin_amdgcn_global_load_lds(
        (const __attribute__((address_space(1))) unsigned int*)g,
        (__attribute__((address_space(3))) unsigned int*)l, 16, 0, 0);
}

__device__ __forceinline__ void cvt8_body(const float* src, __hip_bfloat16* dst, long i) {
    const float4* p = (const float4*)src + i * 2;
    const float4 a = p[0], b = p[1];
    s16x8 r;
    r[0] = f2bs(a.x); r[1] = f2bs(a.y); r[2] = f2bs(a.z); r[3] = f2bs(a.w);
    r[4] = f2bs(b.x); r[5] = f2bs(b.y); r[6] = f2bs(b.z); r[7] = f2bs(b.w);
    *((s16x8*)dst + i) = r;
}

// ---- fused fp32->bf16 convert for x, q_w, k_w, v_w ----
__global__ __launch_bounds__(256) void cvt_xqkv(
    const float* __restrict__ x,  const float* __restrict__ qw,
    const float* __restrict__ kw, const float* __restrict__ vw,
    __hip_bfloat16* __restrict__ xb,  __hip_bfloat16* __restrict__ qwb,
    __hip_bfloat16* __restrict__ kwb, __hip_bfloat16* __restrict__ vwb)
{
    long i = (long)blockIdx.x * 256 + threadIdx.x;  // 8-elem groups, total 1835008
    const float* src; __hip_bfloat16* dst;
    if (i < 1048576)      { src = x;  dst = xb;  }
    else if (i < 1572864) { src = qw; dst = qwb; i -= 1048576; }
    else if (i < 1703936) { src = kw; dst = kwb; i -= 1572864; }
    else                  { src = vw; dst = vwb; i -= 1703936; }
    cvt8_body(src, dst, i);
}

__global__ __launch_bounds__(256) void cvt8(const float* __restrict__ in,
                                            __hip_bfloat16* __restrict__ out, int n8) {
    const int i = blockIdx.x * 256 + threadIdx.x;
    if (i >= n8) return;
    cvt8_body(in, out, i);
}

// ---- fused QKV GEMM: A[4096,2048] @ W[3072,2048]^T, routed epilogue ----
// Q route pre-scales by 0.125*log2(e) so the flash kernel uses bare exp2.
__global__ __launch_bounds__(256) void gemm_qkv(
    const __hip_bfloat16* __restrict__ A,
    const __hip_bfloat16* __restrict__ W,
    const float* __restrict__ qb, const float* __restrict__ kb2,
    const float* __restrict__ vb2,
    __hip_bfloat16* __restrict__ Qb, __hip_bfloat16* __restrict__ Kt,
    __hip_bfloat16* __restrict__ Vt)
{
    const int K = 2048;
    __shared__ __hip_bfloat16 sA[128*32];
    __shared__ __hip_bfloat16 sB[128*32];
    const int tid  = threadIdx.x;
    const int wid  = tid >> 6;
    const int lane = tid & 63;
    const int m0 = blockIdx.x * 128;
    const int n0 = blockIdx.y * 128;
    const int wm = (wid >> 1) * 64;
    const int wn = (wid & 1) * 64;

    f32x4 acc[4][4];
#pragma unroll
    for (int i = 0; i < 4; ++i)
#pragma unroll
        for (int j = 0; j < 4; ++j)
#pragma unroll
            for (int r = 0; r < 4; ++r) acc[i][j][r] = 0.0f;

    const int sr = tid >> 2;
    const int sc = (tid & 3) * 8;
    const __hip_bfloat16* gA = A + (long)(m0 + sr) * K + sc;
    const __hip_bfloat16* gB = W + (long)(n0 + sr) * K + sc;
    __hip_bfloat16* lA = &sA[sr*32 + sc];
    __hip_bfloat16* lB = &sB[sr*32 + sc];

    const int arow0 = wm + (lane & 15);
    const int brow0 = wn + (lane & 15);
    const int koff  = (lane >> 4) * 8;

    for (int kt = 0; kt < 64; ++kt) {
        glds16(gA,              lA);
        glds16(gA + (long)64*K, lA + 64*32);
        glds16(gB,              lB);
        glds16(gB + (long)64*K, lB + 64*32);
        gA += 32; gB += 32;
        __syncthreads();

        s16x8 af[4], bfr[4];
#pragma unroll
        for (int mi = 0; mi < 4; ++mi)
            af[mi] = *(const s16x8*)&sA[(arow0 + mi*16)*32 + koff];
#pragma unroll
        for (int ni = 0; ni < 4; ++ni)
            bfr[ni] = *(const s16x8*)&sB[(brow0 + ni*16)*32 + koff];
#pragma unroll
        for (int mi = 0; mi < 4; ++mi)
#pragma unroll
            for (int ni = 0; ni < 4; ++ni)
                acc[mi][ni] = __builtin_amdgcn_mfma_f32_16x16x32_bf16(
                    af[mi], bfr[ni], acc[mi][ni], 0, 0, 0);
        __syncthreads();
    }

    __hip_bfloat16* C; int ldc, coff; const float* bias;
    float csc = 1.0f;
    if (n0 < 2048)      { C = Qb; ldc = 2048; coff = n0;        bias = qb  + n0;
                          csc = 0.18033688011112042f; }   // 0.125 * log2(e)
    else if (n0 < 2560) { C = Kt; ldc = 512;  coff = n0 - 2048; bias = kb2 + (n0 - 2048); }
    else                { C = Vt; ldc = 512;  coff = n0 - 2560; bias = vb2 + (n0 - 2560); }

    float bvals[4];
#pragma unroll
    for (int ni = 0; ni < 4; ++ni)
        bvals[ni] = bias[wn + ni*16 + (lane & 15)];
#pragma unroll
    for (int mi = 0; mi < 4; ++mi) {
        const int row = m0 + wm + mi*16 + (lane >> 4)*4;
#pragma unroll
        for (int ni = 0; ni < 4; ++ni) {
            const int col = coff + wn + ni*16 + (lane & 15);
#pragma unroll
            for (int r = 0; r < 4; ++r)
                C[(long)(row + r)*ldc + col] =
                    __float2bfloat16((acc[mi][ni][r] + bvals[ni]) * csc);
        }
    }
}

// ---- generic bf16 GEMM (O-projection) ----
template <typename TC>
__global__ __launch_bounds__(256) void gemm_fast(
    const __hip_bfloat16* __restrict__ A,
    const __hip_bfloat16* __restrict__ Bw,
    const float* __restrict__ bias,
    TC* __restrict__ C, int M, int N, int K)
{
    __shared__ __hip_bfloat16 sA[128*32];
    __shared__ __hip_bfloat16 sB[128*32];
    const int tid  = threadIdx.x;
    const int wid  = tid >> 6;
    const int lane = tid & 63;
    const int m0 = blockIdx.x * 128;
    const int n0 = blockIdx.y * 128;
    const int wm = (wid >> 1) * 64;
    const int wn = (wid & 1) * 64;

    f32x4 acc[4][4];
#pragma unroll
    for (int i = 0; i < 4; ++i)
#pragma unroll
        for (int j = 0; j < 4; ++j)
#pragma unroll
            for (int r = 0; r < 4; ++r) acc[i][j][r] = 0.0f;

    const int sr = tid >> 2;
    const int sc = (tid & 3) * 8;
    const __hip_bfloat16* gA = A  + (long)(m0 + sr) * K + sc;
    const __hip_bfloat16* gB = Bw + (long)(n0 + sr) * K + sc;
    __hip_bfloat16* lA = &sA[sr*32 + sc];
    __hip_bfloat16* lB = &sB[sr*32 + sc];

    const int arow0 = wm + (lane & 15);
    const int brow0 = wn + (lane & 15);
    const int koff  = (lane >> 4) * 8;

    const int nk = K >> 5;
    for (int kt = 0; kt < nk; ++kt) {
        glds16(gA,              lA);
        glds16(gA + (long)64*K, lA + 64*32);
        glds16(gB,              lB);
        glds16(gB + (long)64*K, lB + 64*32);
        gA += 32; gB += 32;
        __syncthreads();

        s16x8 af[4], bfr[4];
#pragma unroll
        for (int mi = 0; mi < 4; ++mi)
            af[mi] = *(const s16x8*)&sA[(arow0 + mi*16)*32 + koff];
#pragma unroll
        for (int ni = 0; ni < 4; ++ni)
            bfr[ni] = *(const s16x8*)&sB[(brow0 + ni*16)*32 + koff];
#pragma unroll
        for (int mi = 0; mi < 4; ++mi)
#pragma unroll
            for (int ni = 0; ni < 4; ++ni)
                acc[mi][ni] = __builtin_amdgcn_mfma_f32_16x16x32_bf16(
                    af[mi], bfr[ni], acc[mi][ni], 0, 0, 0);
        __syncthreads();
    }

    float bvals[4];
#pragma unroll
    for (int ni = 0; ni < 4; ++ni)
        bvals[ni] = bias[n0 + wn + ni*16 + (lane & 15)];
#pragma unroll
    for (int mi = 0; mi < 4; ++mi) {
        const int row = m0 + wm + mi*16 + (lane >> 4)*4;
#pragma unroll
        for (int ni = 0; ni < 4; ++ni) {
            const int col = n0 + wn + ni*16 + (lane & 15);
#pragma unroll
            for (int r = 0; r < 4; ++r)
                store1(&C[(long)(row + r)*N + col], acc[mi][ni][r] + bvals[ni]);
        }
    }
}

// ---- fallback GEMM with fused fp32->bf16 convert ----
template <typename TA, typename TC>
__global__ __launch_bounds__(256) void gemm_bt_bias(
    const TA* __restrict__ A, const float* __restrict__ Bw,
    const float* __restrict__ bias, TC* __restrict__ C,
    int M, int N, int K, float scale)
{
    __shared__ __hip_bfloat16 sA[128*32];
    __shared__ __hip_bfloat16 sB[128*32];
    const int tid  = threadIdx.x;
    const int wid  = tid >> 6;
    const int lane = tid & 63;
    const int m0 = blockIdx.x * 128;
    const int n0 = blockIdx.y * 128;
    const int wm = (wid >> 1) * 64;
    const int wn = (wid & 1) * 64;

    f32x4 acc[4][4];
#pragma unroll
    for (int i = 0; i < 4; ++i)
#pragma unroll
        for (int j = 0; j < 4; ++j)
#pragma unroll
            for (int r = 0; r < 4; ++r) acc[i][j][r] = 0.0f;

    const int sr = tid >> 3;
    const int sc = (tid & 7) * 4;
    const TA*    gA = A  + (long)(m0 + sr) * K + sc;
    const float* gB = Bw + (long)(n0 + sr) * K + sc;

    const int arow0 = wm + (lane & 15);
    const int brow0 = wn + (lane & 15);
    const int koff  = (lane >> 4) * 8;

    const int nk = K >> 5;
    for (int kt = 0; kt < nk; ++kt) {
        s16x4 a0 = load4_bf16(gA);
        s16x4 a1 = load4_bf16(gA + (long)32*K);
        s16x4 a2 = load4_bf16(gA + (long)64*K);
        s16x4 a3 = load4_bf16(gA + (long)96*K);
        s16x4 b0 = load4_bf16(gB);
        s16x4 b1 = load4_bf16(gB + (long)32*K);
        s16x4 b2 = load4_bf16(gB + (long)64*K);
        s16x4 b3 = load4_bf16(gB + (long)96*K);
        gA += 32; gB += 32;
        *(s16x4*)&sA[(sr     )*32 + sc] = a0;
        *(s16x4*)&sA[(sr + 32)*32 + sc] = a1;
        *(s16x4*)&sA[(sr + 64)*32 + sc] = a2;
        *(s16x4*)&sA[(sr + 96)*32 + sc] = a3;
        *(s16x4*)&sB[(sr     )*32 + sc] = b0;
        *(s16x4*)&sB[(sr + 32)*32 + sc] = b1;
        *(s16x4*)&sB[(sr + 64)*32 + sc] = b2;
        *(s16x4*)&sB[(sr + 96)*32 + sc] = b3;
        __syncthreads();

        s16x8 af[4], bfr[4];
#pragma unroll
        for (int mi = 0; mi < 4; ++mi)
            af[mi] = *(const s16x8*)&sA[(arow0 + mi*16)*32 + koff];
#pragma unroll
        for (int ni = 0; ni < 4; ++ni)
            bfr[ni] = *(const s16x8*)&sB[(brow0 + ni*16)*32 + koff];
#pragma unroll
        for (int mi = 0; mi < 4; ++mi)
#pragma unroll
            for (int ni = 0; ni < 4; ++ni)
                acc[mi][ni] = __builtin_amdgcn_mfma_f32_16x16x32_bf16(
                    af[mi], bfr[ni], acc[mi][ni], 0, 0, 0);
        __syncthreads();
    }

    float bvals[4];
#pragma unroll
    for (int ni = 0; ni < 4; ++ni)
        bvals[ni] = bias[n0 + wn + ni*16 + (lane & 15)];
#pragma unroll
    for (int mi = 0; mi < 4; ++mi) {
        const int row = m0 + wm + mi*16 + (lane >> 4)*4;
#pragma unroll
        for (int ni = 0; ni < 4; ++ni) {
            const int col = n0 + wn + ni*16 + (lane & 15);
#pragma unroll
            for (int r = 0; r < 4; ++r)
                store1(&C[(long)(row + r)*N + col],
                       (acc[mi][ni][r] + bvals[ni]) * scale);
        }
    }
}

// ---- Flash GQA v15: round-9 verified structure + T5 s_setprio around the
//      MFMA clusters ONLY (isolating the setprio variable from round 6's
//      bundle; blocks are independent so waves diverge between barriers ->
//      the scheduler has MFMA vs memory waves to arbitrate, m191 regime). ----
#define LDK 72
#define LDV 72

__global__ __launch_bounds__(512, 6) void gqa_flash(
    const __hip_bfloat16* __restrict__ Q,
    const __hip_bfloat16* __restrict__ Kb,
    const __hip_bfloat16* __restrict__ Vb,
    const int* __restrict__ amask,
    __hip_bfloat16* __restrict__ O)
{
    __shared__ __hip_bfloat16 sK[2][64*LDK];
    __shared__ __hip_bfloat16 sVt[2][64*LDV];

    const int tid  = threadIdx.x;
    const int wid  = tid >> 6;
    const int lane = tid & 63;
    const int bx = blockIdx.x;
    const int bh = blockIdx.y;
    const int b  = bh >> 5;
    const int h  = bh & 31;
    const int kv = h >> 2;

    const __hip_bfloat16* Kg = Kb + (long)(b*L_)*512 + kv*DH;
    const __hip_bfloat16* Vg = Vb + (long)(b*L_)*512 + kv*DH;
    const int* mg = amask + b*L_;

    const int lcol = lane & 15;
    const int g    = lane >> 4;

    const int kr = tid >> 3;
    const int kc = (tid & 7) * 8;
    const int vj = (tid & 31) * 2;
    const int vd = (tid >> 5) * 4;
    const int qsr = tid >> 2;
    const int qsc = (tid & 3) * 16;

    const f32x4 z4 = {0.0f, 0.0f, 0.0f, 0.0f};   // hoisted MFMA C-zero

    for (int ph = 0; ph < 2; ++ph) {
        const int qt = ph ? (15 - bx) : bx;
        const int jmax = 2*qt + 1;
        const __hip_bfloat16* Qg = Q + (long)(b*L_ + qt*128)*HID + h*DH;

        __syncthreads();
        {
            s16x8 q0 = *(const s16x8*)(Qg + (long)qsr*HID + qsc);
            s16x8 q1 = *(const s16x8*)(Qg + (long)qsr*HID + qsc + 8);
            __hip_bfloat16* dst = (qsr < 64) ? &sK[0][qsr*LDK + qsc]
                                             : &sK[1][(qsr-64)*LDK + qsc];
            *(s16x8*)&dst[0] = q0;
            *(s16x8*)&dst[8] = q1;
        }
        __syncthreads();
        s16x8 qf[2];
        {
            const __hip_bfloat16* qbuf = (wid < 4)
                ? &sK[0][((wid & 3)*16 + lcol)*LDK]
                : &sK[1][((wid & 3)*16 + lcol)*LDK];
            qf[0] = *(const s16x8*)&qbuf[g*8];
            qf[1] = *(const s16x8*)&qbuf[32 + g*8];
        }
        __syncthreads();

        {
            s16x8 k0 = *(const s16x8*)(Kg + (long)kr*512 + kc);
            *(s16x8*)&sK[0][kr*LDK + kc] = k0;
            s16x4 v0 = *(const s16x4*)(Vg + (long)vj*512 + vd);
            s16x4 v1 = *(const s16x4*)(Vg + (long)(vj+1)*512 + vd);
            short* sv = (short*)sVt[0];
#pragma unroll
            for (int i = 0; i < 4; ++i) {
                s16x2 pr; pr.x = v0[i]; pr.y = v1[i];
                *(s16x2*)&sv[(vd+i)*LDV + vj] = pr;
            }
        }

        float lrl = 0.0f;
        f32x4 oacc[4];
#pragma unroll
        for (int nt = 0; nt < 4; ++nt)
#pragma unroll
            for (int r = 0; r < 4; ++r) oacc[nt][r] = 0.0f;

        for (int jt = 0; jt <= jmax; ++jt) {
            const int cur = jt & 1;
            __syncthreads();

            // unguarded prefetch of tile jt+1 (over-read lands in live ws, discarded)
            const long pno = (long)((jt + 1)*64) * 512;
            s16x8 kreg = *(const s16x8*)(Kg + pno + (long)kr*512 + kc);
            s16x4 v0r  = *(const s16x4*)(Vg + pno + (long)vj*512 + vd);
            s16x4 v1r  = *(const s16x4*)(Vg + pno + (long)(vj+1)*512 + vd);
            const int mv = mg[jt*64 + lane];
            const unsigned long long bal = __ballot(mv == 0);

            f32x4 sacc[4];
            __builtin_amdgcn_s_setprio(1);
#pragma unroll
            for (int ct = 0; ct < 4; ++ct) {
                s16x8 kf = *(const s16x8*)&sK[cur][(ct*16 + lcol)*LDK + g*8];
                sacc[ct] = __builtin_amdgcn_mfma_f32_16x16x32_bf16(
                    kf, qf[0], z4, 0, 0, 0);
            }
#pragma unroll
            for (int ct = 0; ct < 4; ++ct) {
                s16x8 kf = *(const s16x8*)&sK[cur][(ct*16 + lcol)*LDK + 32 + g*8];
                sacc[ct] = __builtin_amdgcn_mfma_f32_16x16x32_bf16(
                    kf, qf[1], sacc[ct], 0, 0, 0);
            }
            __builtin_amdgcn_s_setprio(0);

            if (bal) {
#pragma unroll
                for (int ct = 0; ct < 4; ++ct) {
                    const unsigned nib = (unsigned)(bal >> (ct*16 + g*4)) & 15u;
#pragma unroll
                    for (int r = 0; r < 4; ++r)
                        if (nib & (1u << r)) sacc[ct][r] = -2.0e5f;
                }
            }
            if (jt >= 2*qt) {
                const int qrow = qt*128 + wid*16 + lcol;
#pragma unroll
                for (int ct = 0; ct < 4; ++ct) {
                    const int jb = jt*64 + ct*16 + g*4;
#pragma unroll
                    for (int r = 0; r < 4; ++r)
                        if (jb + r > qrow) sacc[ct][r] = -2.0e5f;
                }
            }

            // no-max softmax: Q pre-scaled by 0.125*log2e, so p = 2^s directly.
            // Pack P rows into registers: Wlo[ct] = (p0,p1), Whi[ct] = (p2,p3).
            unsigned Wlo[4], Whi[4];
            float ps = 0.0f;
#pragma unroll
            for (int ct = 0; ct < 4; ++ct) {
                const float p0 = __builtin_amdgcn_exp2f(sacc[ct][0]);
                const float p1 = __builtin_amdgcn_exp2f(sacc[ct][1]);
                const float p2 = __builtin_amdgcn_exp2f(sacc[ct][2]);
                const float p3 = __builtin_amdgcn_exp2f(sacc[ct][3]);
                ps += (p0 + p1) + (p2 + p3);
                Wlo[ct] = pkbf_fast(p0, p1);
                Whi[ct] = pkbf_fast(p2, p3);
            }
            lrl += ps;

            // PV with in-register P exchange (replaces the sPp LDS round-trip):
            // C = swap16(swap32(X,Y)).first -> pu words from writer w0=(2g)&3,
            // D = .second -> words from w1=(2g+1)&3; ct-selection by g>>1 falls
            // out of the 32-swap. Verified equal to the old myP read pattern.
#pragma unroll
            for (int ks = 0; ks < 2; ++ks) {
                unsigned c0 = Wlo[ks*2], d0 = Wlo[ks*2 + 1];
                unsigned c1 = Whi[ks*2], d1 = Whi[ks*2 + 1];
                pl_swap32(c0, d0); pl_swap16(c0, d0);
                pl_swap32(c1, d1); pl_swap16(c1, d1);
                u32x4 pu; pu.x = c0; pu.y = c1; pu.z = d0; pu.w = d1;
                const s16x8 pf = __builtin_bit_cast(s16x8, pu);
                __builtin_amdgcn_s_setprio(1);
#pragma unroll
                for (int nt = 0; nt < 4; ++nt) {
                    s16x8 vf = *(const s16x8*)&sVt[cur][(nt*16 + lcol)*LDV + ks*32 + g*8];
                    oacc[nt] = __builtin_amdgcn_mfma_f32_16x16x32_bf16(
                        pf, vf, oacc[nt], 0, 0, 0);
                }
                __builtin_amdgcn_s_setprio(0);
            }

            // stage next tile at iteration end (keeps V-reads ahead of these
            // in the in-order DS queue; the loop-top barrier drains them)
            if (jt < jmax) {
                const int nb = cur ^ 1;
                *(s16x8*)&sK[nb][kr*LDK + kc] = kreg;
                short* sv = (short*)sVt[nb];
#pragma unroll
                for (int i = 0; i < 4; ++i) {
                    s16x2 pr; pr.x = v0r[i]; pr.y = v1r[i];
                    *(s16x2*)&sv[(vd+i)*LDV + vj] = pr;
                }
            }
        }

        // epilogue: reduce row sums (only cross-lane step), normalize, store
        lrl += __shfl_xor(lrl, 16);
        lrl += __shfl_xor(lrl, 32);
        const float inv = 1.0f / lrl;
        float invr[4];
#pragma unroll
        for (int r = 0; r < 4; ++r)
            invr[r] = bpermf((g*4 + r) << 2, inv);

        __hip_bfloat16* Og = O + (long)(b*L_ + qt*128)*HID + h*DH;
#pragma unroll
        for (int r = 0; r < 4; ++r) {
            const int row = wid*16 + g*4 + r;
#pragma unroll
            for (int nt = 0; nt < 4; ++nt)
                Og[(long)row*HID + nt*16 + lcol] =
                    __float2bfloat16(oacc[nt][r] * invr[r]);
        }
    }
}

extern "C" void kernel_launch(void* const* d_in, const int* in_sizes, int n_in,
                              void* d_out, int out_size, void* d_ws, size_t ws_size,
                              hipStream_t stream) {
    const float* x   = (const float*)d_in[0];
    const int*   am  = (const int*)d_in[1];
    const float* q_w = (const float*)d_in[2];
    const float* q_b = (const float*)d_in[3];
    const float* k_w = (const float*)d_in[4];
    const float* k_b = (const float*)d_in[5];
    const float* v_w = (const float*)d_in[6];
    const float* v_b = (const float*)d_in[7];
    const float* o_w = (const float*)d_in[8];
    const float* o_b = (const float*)d_in[9];
    float* out = (float*)d_out;
    char* ws = (char*)d_ws;
    dim3 blk(256);
    const float qsc = 0.18033688011112042f;   // 0.125 * log2(e)

    if (ws_size >= 37748736) {
        __hip_bfloat16* Qb   = (__hip_bfloat16*)d_out;
        __hip_bfloat16* xb   = (__hip_bfloat16*)((char*)d_out + 16777216);
        __hip_bfloat16* wcat = (__hip_bfloat16*)(ws);
        __hip_bfloat16* qwb  = (__hip_bfloat16*)(ws);
        __hip_bfloat16* kwb  = (__hip_bfloat16*)(ws + 8388608);
        __hip_bfloat16* vwb  = (__hip_bfloat16*)(ws + 10485760);
        __hip_bfloat16* Kt   = (__hip_bfloat16*)(ws + 12582912);
        __hip_bfloat16* Vt   = (__hip_bfloat16*)(ws + 16777216);
        __hip_bfloat16* Ob   = (__hip_bfloat16*)(ws + 20971520);
        __hip_bfloat16* owb  = qwb;   // reuse after QKV GEMM (stream-ordered)

        cvt_xqkv<<<7168, blk, 0, stream>>>(x, q_w, k_w, v_w, xb, qwb, kwb, vwb);
        gemm_qkv<<<dim3(32, 24), blk, 0, stream>>>(xb, wcat, q_b, k_b, v_b, Qb, Kt, Vt);
        cvt8<<<2048, blk, 0, stream>>>(o_w, owb, 524288);
        gqa_flash<<<dim3(8, 64), dim3(512), 0, stream>>>(Qb, Kt, Vt, am, Ob);
        gemm_fast<float><<<dim3(32, 16), blk, 0, stream>>>(Ob, owb, o_b, out, 4096, 2048, 2048);
    } else {
        __hip_bfloat16* Qb = (__hip_bfloat16*)d_out;
        __hip_bfloat16* Kt = (__hip_bfloat16*)(ws);
        __hip_bfloat16* Vt = (__hip_bfloat16*)(ws + 4194304);
        __hip_bfloat16* Ob = (__hip_bfloat16*)(ws + 8388608);
        gemm_bt_bias<float, __hip_bfloat16><<<dim3(32,16), blk, 0, stream>>>(x, q_w, q_b, Qb, 4096, 2048, 2048, qsc);
        gemm_bt_bias<float, __hip_bfloat16><<<dim3(32, 4), blk, 0, stream>>>(x, k_w, k_b, Kt, 4096,  512, 2048, 1.0f);
        gemm_bt_bias<float, __hip_bfloat16><<<dim3(32, 4), blk, 0, stream>>>(x, v_w, v_b, Vt, 4096,  512, 2048, 1.0f);
        gqa_flash<<<dim3(8, 64), dim3(512), 0, stream>>>(Qb, Kt, Vt, am, Ob);
        gemm_bt_bias<__hip_bfloat16, float><<<dim3(32,16), blk, 0, stream>>>(Ob, o_w, o_b, out, 4096, 2048, 2048, 1.0f);
    }
}

// Round 11
// 298.365 us; speedup vs baseline: 1.0183x; 1.0183x over previous
//
#include <hip/hip_runtime.h>
#include <hip/hip_bf16.h>

typedef __attribute__((ext_vector_type(8))) short s16x8;
typedef __attribute__((ext_vector_type(4))) short s16x4;
typedef __attribute__((ext_vector_type(2))) short s16x2;
typedef __attribute__((ext_vector_type(4))) float f32x4;
typedef __attribute__((ext_vector_type(4))) unsigned int u32x4;

#define L_ 2048
#define HID 2048
#define DH 64

__device__ __forceinline__ short f2bs(float f) {
    __hip_bfloat16 h = __float2bfloat16(f);
    return *reinterpret_cast<short*>(&h);
}
// fast bf16x2 pack: round-half-up + v_perm_b32. a -> low16, b -> high16.
__device__ __forceinline__ unsigned int pkbf_fast(float a, float b) {
    unsigned ua = __builtin_bit_cast(unsigned, a) + 0x8000u;
    unsigned ub = __builtin_bit_cast(unsigned, b) + 0x8000u;
    return __builtin_amdgcn_perm(ub, ua, 0x07060302u);
}
__device__ __forceinline__ float bpermf(int byteidx, float v) {
    int r = __builtin_amdgcn_ds_bpermute(byteidx, __builtin_bit_cast(int, v));
    return __builtin_bit_cast(float, r);
}
// dual-register lane-block swaps (VALU cross-lane, not DS pipe):
// pl_swap32: a' = {a.lanes0-31, b.lanes0-31}, b' = {a.lanes32-63, b.lanes32-63}
__device__ __forceinline__ void pl_swap32(unsigned &a, unsigned &b) {
    asm volatile("v_permlane32_swap_b32 %0, %1" : "+v"(a), "+v"(b));
}
// pl_swap16: a' = {a.q0, b.q0, a.q2, b.q2}, b' = {a.q1, b.q1, a.q3, b.q3}
__device__ __forceinline__ void pl_swap16(unsigned &a, unsigned &b) {
    asm volatile("v_permlane16_swap_b32 %0, %1" : "+v"(a), "+v"(b));
}
__device__ __forceinline__ s16x4 load4_bf16(const float* p) {
    const float4 v = *(const float4*)p;
    s16x4 r; r.x = f2bs(v.x); r.y = f2bs(v.y); r.z = f2bs(v.z); r.w = f2bs(v.w);
    return r;
}
__device__ __forceinline__ s16x4 load4_bf16(const __hip_bfloat16* p) {
    return *(const s16x4*)p;
}
__device__ __forceinline__ void store1(float* p, float v) { *p = v; }
__device__ __forceinline__ void store1(__hip_bfloat16* p, float v) { *p = __float2bfloat16(v); }

__device__ __forceinline__ void glds16(const __hip_bfloat16* g, __hip_bfloat16* l) {
    __builtin_amdgcn_global_load_lds(
        (const __attribute__((address_space(1))) unsigned int*)g,
        (__attribute__((address_space(3))) unsigned int*)l, 16, 0, 0);
}

__device__ __forceinline__ void cvt8_body(const float* src, __hip_bfloat16* dst, long i) {
    const float4* p = (const float4*)src + i * 2;
    const float4 a = p[0], b = p[1];
    s16x8 r;
    r[0] = f2bs(a.x); r[1] = f2bs(a.y); r[2] = f2bs(a.z); r[3] = f2bs(a.w);
    r[4] = f2bs(b.x); r[5] = f2bs(b.y); r[6] = f2bs(b.z); r[7] = f2bs(b.w);
    *((s16x8*)dst + i) = r;
}

// ---- fused fp32->bf16 convert for x, q_w, k_w, v_w ----
__global__ __launch_bounds__(256) void cvt_xqkv(
    const float* __restrict__ x,  const float* __restrict__ qw,
    const float* __restrict__ kw, const float* __restrict__ vw,
    __hip_bfloat16* __restrict__ xb,  __hip_bfloat16* __restrict__ qwb,
    __hip_bfloat16* __restrict__ kwb, __hip_bfloat16* __restrict__ vwb)
{
    long i = (long)blockIdx.x * 256 + threadIdx.x;  // 8-elem groups, total 1835008
    const float* src; __hip_bfloat16* dst;
    if (i < 1048576)      { src = x;  dst = xb;  }
    else if (i < 1572864) { src = qw; dst = qwb; i -= 1048576; }
    else if (i < 1703936) { src = kw; dst = kwb; i -= 1572864; }
    else                  { src = vw; dst = vwb; i -= 1703936; }
    cvt8_body(src, dst, i);
}

__global__ __launch_bounds__(256) void cvt8(const float* __restrict__ in,
                                            __hip_bfloat16* __restrict__ out, int n8) {
    const int i = blockIdx.x * 256 + threadIdx.x;
    if (i >= n8) return;
    cvt8_body(in, out, i);
}

// ---- fused QKV GEMM: A[4096,2048] @ W[3072,2048]^T, routed epilogue ----
// Q route pre-scales by 0.125*log2(e) so the flash kernel uses bare exp2.
__global__ __launch_bounds__(256) void gemm_qkv(
    const __hip_bfloat16* __restrict__ A,
    const __hip_bfloat16* __restrict__ W,
    const float* __restrict__ qb, const float* __restrict__ kb2,
    const float* __restrict__ vb2,
    __hip_bfloat16* __restrict__ Qb, __hip_bfloat16* __restrict__ Kt,
    __hip_bfloat16* __restrict__ Vt)
{
    const int K = 2048;
    __shared__ __hip_bfloat16 sA[128*32];
    __shared__ __hip_bfloat16 sB[128*32];
    const int tid  = threadIdx.x;
    const int wid  = tid >> 6;
    const int lane = tid & 63;
    const int m0 = blockIdx.x * 128;
    const int n0 = blockIdx.y * 128;
    const int wm = (wid >> 1) * 64;
    const int wn = (wid & 1) * 64;

    f32x4 acc[4][4];
#pragma unroll
    for (int i = 0; i < 4; ++i)
#pragma unroll
        for (int j = 0; j < 4; ++j)
#pragma unroll
            for (int r = 0; r < 4; ++r) acc[i][j][r] = 0.0f;

    const int sr = tid >> 2;
    const int sc = (tid & 3) * 8;
    const __hip_bfloat16* gA = A + (long)(m0 + sr) * K + sc;
    const __hip_bfloat16* gB = W + (long)(n0 + sr) * K + sc;
    __hip_bfloat16* lA = &sA[sr*32 + sc];
    __hip_bfloat16* lB = &sB[sr*32 + sc];

    const int arow0 = wm + (lane & 15);
    const int brow0 = wn + (lane & 15);
    const int koff  = (lane >> 4) * 8;

    for (int kt = 0; kt < 64; ++kt) {
        glds16(gA,              lA);
        glds16(gA + (long)64*K, lA + 64*32);
        glds16(gB,              lB);
        glds16(gB + (long)64*K, lB + 64*32);
        gA += 32; gB += 32;
        __syncthreads();

        s16x8 af[4], bfr[4];
#pragma unroll
        for (int mi = 0; mi < 4; ++mi)
            af[mi] = *(const s16x8*)&sA[(arow0 + mi*16)*32 + koff];
#pragma unroll
        for (int ni = 0; ni < 4; ++ni)
            bfr[ni] = *(const s16x8*)&sB[(brow0 + ni*16)*32 + koff];
#pragma unroll
        for (int mi = 0; mi < 4; ++mi)
#pragma unroll
            for (int ni = 0; ni < 4; ++ni)
                acc[mi][ni] = __builtin_amdgcn_mfma_f32_16x16x32_bf16(
                    af[mi], bfr[ni], acc[mi][ni], 0, 0, 0);
        __syncthreads();
    }

    __hip_bfloat16* C; int ldc, coff; const float* bias;
    float csc = 1.0f;
    if (n0 < 2048)      { C = Qb; ldc = 2048; coff = n0;        bias = qb  + n0;
                          csc = 0.18033688011112042f; }   // 0.125 * log2(e)
    else if (n0 < 2560) { C = Kt; ldc = 512;  coff = n0 - 2048; bias = kb2 + (n0 - 2048); }
    else                { C = Vt; ldc = 512;  coff = n0 - 2560; bias = vb2 + (n0 - 2560); }

    float bvals[4];
#pragma unroll
    for (int ni = 0; ni < 4; ++ni)
        bvals[ni] = bias[wn + ni*16 + (lane & 15)];
#pragma unroll
    for (int mi = 0; mi < 4; ++mi) {
        const int row = m0 + wm + mi*16 + (lane >> 4)*4;
#pragma unroll
        for (int ni = 0; ni < 4; ++ni) {
            const int col = coff + wn + ni*16 + (lane & 15);
#pragma unroll
            for (int r = 0; r < 4; ++r)
                C[(long)(row + r)*ldc + col] =
                    __float2bfloat16((acc[mi][ni][r] + bvals[ni]) * csc);
        }
    }
}

// ---- generic bf16 GEMM (O-projection) ----
template <typename TC>
__global__ __launch_bounds__(256) void gemm_fast(
    const __hip_bfloat16* __restrict__ A,
    const __hip_bfloat16* __restrict__ Bw,
    const float* __restrict__ bias,
    TC* __restrict__ C, int M, int N, int K)
{
    __shared__ __hip_bfloat16 sA[128*32];
    __shared__ __hip_bfloat16 sB[128*32];
    const int tid  = threadIdx.x;
    const int wid  = tid >> 6;
    const int lane = tid & 63;
    const int m0 = blockIdx.x * 128;
    const int n0 = blockIdx.y * 128;
    const int wm = (wid >> 1) * 64;
    const int wn = (wid & 1) * 64;

    f32x4 acc[4][4];
#pragma unroll
    for (int i = 0; i < 4; ++i)
#pragma unroll
        for (int j = 0; j < 4; ++j)
#pragma unroll
            for (int r = 0; r < 4; ++r) acc[i][j][r] = 0.0f;

    const int sr = tid >> 2;
    const int sc = (tid & 3) * 8;
    const __hip_bfloat16* gA = A  + (long)(m0 + sr) * K + sc;
    const __hip_bfloat16* gB = Bw + (long)(n0 + sr) * K + sc;
    __hip_bfloat16* lA = &sA[sr*32 + sc];
    __hip_bfloat16* lB = &sB[sr*32 + sc];

    const int arow0 = wm + (lane & 15);
    const int brow0 = wn + (lane & 15);
    const int koff  = (lane >> 4) * 8;

    const int nk = K >> 5;
    for (int kt = 0; kt < nk; ++kt) {
        glds16(gA,              lA);
        glds16(gA + (long)64*K, lA + 64*32);
        glds16(gB,              lB);
        glds16(gB + (long)64*K, lB + 64*32);
        gA += 32; gB += 32;
        __syncthreads();

        s16x8 af[4], bfr[4];
#pragma unroll
        for (int mi = 0; mi < 4; ++mi)
            af[mi] = *(const s16x8*)&sA[(arow0 + mi*16)*32 + koff];
#pragma unroll
        for (int ni = 0; ni < 4; ++ni)
            bfr[ni] = *(const s16x8*)&sB[(brow0 + ni*16)*32 + koff];
#pragma unroll
        for (int mi = 0; mi < 4; ++mi)
#pragma unroll
            for (int ni = 0; ni < 4; ++ni)
                acc[mi][ni] = __builtin_amdgcn_mfma_f32_16x16x32_bf16(
                    af[mi], bfr[ni], acc[mi][ni], 0, 0, 0);
        __syncthreads();
    }

    float bvals[4];
#pragma unroll
    for (int ni = 0; ni < 4; ++ni)
        bvals[ni] = bias[n0 + wn + ni*16 + (lane & 15)];
#pragma unroll
    for (int mi = 0; mi < 4; ++mi) {
        const int row = m0 + wm + mi*16 + (lane >> 4)*4;
#pragma unroll
        for (int ni = 0; ni < 4; ++ni) {
            const int col = n0 + wn + ni*16 + (lane & 15);
#pragma unroll
            for (int r = 0; r < 4; ++r)
                store1(&C[(long)(row + r)*N + col], acc[mi][ni][r] + bvals[ni]);
        }
    }
}

// ---- fallback GEMM with fused fp32->bf16 convert ----
template <typename TA, typename TC>
__global__ __launch_bounds__(256) void gemm_bt_bias(
    const TA* __restrict__ A, const float* __restrict__ Bw,
    const float* __restrict__ bias, TC* __restrict__ C,
    int M, int N, int K, float scale)
{
    __shared__ __hip_bfloat16 sA[128*32];
    __shared__ __hip_bfloat16 sB[128*32];
    const int tid  = threadIdx.x;
    const int wid  = tid >> 6;
    const int lane = tid & 63;
    const int m0 = blockIdx.x * 128;
    const int n0 = blockIdx.y * 128;
    const int wm = (wid >> 1) * 64;
    const int wn = (wid & 1) * 64;

    f32x4 acc[4][4];
#pragma unroll
    for (int i = 0; i < 4; ++i)
#pragma unroll
        for (int j = 0; j < 4; ++j)
#pragma unroll
            for (int r = 0; r < 4; ++r) acc[i][j][r] = 0.0f;

    const int sr = tid >> 3;
    const int sc = (tid & 7) * 4;
    const TA*    gA = A  + (long)(m0 + sr) * K + sc;
    const float* gB = Bw + (long)(n0 + sr) * K + sc;

    const int arow0 = wm + (lane & 15);
    const int brow0 = wn + (lane & 15);
    const int koff  = (lane >> 4) * 8;

    const int nk = K >> 5;
    for (int kt = 0; kt < nk; ++kt) {
        s16x4 a0 = load4_bf16(gA);
        s16x4 a1 = load4_bf16(gA + (long)32*K);
        s16x4 a2 = load4_bf16(gA + (long)64*K);
        s16x4 a3 = load4_bf16(gA + (long)96*K);
        s16x4 b0 = load4_bf16(gB);
        s16x4 b1 = load4_bf16(gB + (long)32*K);
        s16x4 b2 = load4_bf16(gB + (long)64*K);
        s16x4 b3 = load4_bf16(gB + (long)96*K);
        gA += 32; gB += 32;
        *(s16x4*)&sA[(sr     )*32 + sc] = a0;
        *(s16x4*)&sA[(sr + 32)*32 + sc] = a1;
        *(s16x4*)&sA[(sr + 64)*32 + sc] = a2;
        *(s16x4*)&sA[(sr + 96)*32 + sc] = a3;
        *(s16x4*)&sB[(sr     )*32 + sc] = b0;
        *(s16x4*)&sB[(sr + 32)*32 + sc] = b1;
        *(s16x4*)&sB[(sr + 64)*32 + sc] = b2;
        *(s16x4*)&sB[(sr + 96)*32 + sc] = b3;
        __syncthreads();

        s16x8 af[4], bfr[4];
#pragma unroll
        for (int mi = 0; mi < 4; ++mi)
            af[mi] = *(const s16x8*)&sA[(arow0 + mi*16)*32 + koff];
#pragma unroll
        for (int ni = 0; ni < 4; ++ni)
            bfr[ni] = *(const s16x8*)&sB[(brow0 + ni*16)*32 + koff];
#pragma unroll
        for (int mi = 0; mi < 4; ++mi)
#pragma unroll
            for (int ni = 0; ni < 4; ++ni)
                acc[mi][ni] = __builtin_amdgcn_mfma_f32_16x16x32_bf16(
                    af[mi], bfr[ni], acc[mi][ni], 0, 0, 0);
        __syncthreads();
    }

    float bvals[4];
#pragma unroll
    for (int ni = 0; ni < 4; ++ni)
        bvals[ni] = bias[n0 + wn + ni*16 + (lane & 15)];
#pragma unroll
    for (int mi = 0; mi < 4; ++mi) {
        const int row = m0 + wm + mi*16 + (lane >> 4)*4;
#pragma unroll
        for (int ni = 0; ni < 4; ++ni) {
            const int col = n0 + wn + ni*16 + (lane & 15);
#pragma unroll
            for (int r = 0; r < 4; ++r)
                store1(&C[(long)(row + r)*N + col],
                       (acc[mi][ni][r] + bvals[ni]) * scale);
        }
    }
}

// ---- Flash GQA v14 (FINAL): round-7 structure + hoisted-zero QK accumulator.
//      Verified best: permlane P exchange (no sPp LDS round-trip), balanced
//      2-phase q-tile pairing, Q pre-scaled upstream, bare v_exp_f32 softmax.
//      setprio removed (round-10 A/B: null-to-negative in this barrier-synced
//      wave structure). ----
#define LDK 72
#define LDV 72

__global__ __launch_bounds__(512, 6) void gqa_flash(
    const __hip_bfloat16* __restrict__ Q,
    const __hip_bfloat16* __restrict__ Kb,
    const __hip_bfloat16* __restrict__ Vb,
    const int* __restrict__ amask,
    __hip_bfloat16* __restrict__ O)
{
    __shared__ __hip_bfloat16 sK[2][64*LDK];
    __shared__ __hip_bfloat16 sVt[2][64*LDV];

    const int tid  = threadIdx.x;
    const int wid  = tid >> 6;
    const int lane = tid & 63;
    const int bx = blockIdx.x;
    const int bh = blockIdx.y;
    const int b  = bh >> 5;
    const int h  = bh & 31;
    const int kv = h >> 2;

    const __hip_bfloat16* Kg = Kb + (long)(b*L_)*512 + kv*DH;
    const __hip_bfloat16* Vg = Vb + (long)(b*L_)*512 + kv*DH;
    const int* mg = amask + b*L_;

    const int lcol = lane & 15;
    const int g    = lane >> 4;

    const int kr = tid >> 3;
    const int kc = (tid & 7) * 8;
    const int vj = (tid & 31) * 2;
    const int vd = (tid >> 5) * 4;
    const int qsr = tid >> 2;
    const int qsc = (tid & 3) * 16;

    const f32x4 z4 = {0.0f, 0.0f, 0.0f, 0.0f};   // hoisted MFMA C-zero

    for (int ph = 0; ph < 2; ++ph) {
        const int qt = ph ? (15 - bx) : bx;
        const int jmax = 2*qt + 1;
        const __hip_bfloat16* Qg = Q + (long)(b*L_ + qt*128)*HID + h*DH;

        __syncthreads();
        {
            s16x8 q0 = *(const s16x8*)(Qg + (long)qsr*HID + qsc);
            s16x8 q1 = *(const s16x8*)(Qg + (long)qsr*HID + qsc + 8);
            __hip_bfloat16* dst = (qsr < 64) ? &sK[0][qsr*LDK + qsc]
                                             : &sK[1][(qsr-64)*LDK + qsc];
            *(s16x8*)&dst[0] = q0;
            *(s16x8*)&dst[8] = q1;
        }
        __syncthreads();
        s16x8 qf[2];
        {
            const __hip_bfloat16* qbuf = (wid < 4)
                ? &sK[0][((wid & 3)*16 + lcol)*LDK]
                : &sK[1][((wid & 3)*16 + lcol)*LDK];
            qf[0] = *(const s16x8*)&qbuf[g*8];
            qf[1] = *(const s16x8*)&qbuf[32 + g*8];
        }
        __syncthreads();

        {
            s16x8 k0 = *(const s16x8*)(Kg + (long)kr*512 + kc);
            *(s16x8*)&sK[0][kr*LDK + kc] = k0;
            s16x4 v0 = *(const s16x4*)(Vg + (long)vj*512 + vd);
            s16x4 v1 = *(const s16x4*)(Vg + (long)(vj+1)*512 + vd);
            short* sv = (short*)sVt[0];
#pragma unroll
            for (int i = 0; i < 4; ++i) {
                s16x2 pr; pr.x = v0[i]; pr.y = v1[i];
                *(s16x2*)&sv[(vd+i)*LDV + vj] = pr;
            }
        }

        float lrl = 0.0f;
        f32x4 oacc[4];
#pragma unroll
        for (int nt = 0; nt < 4; ++nt)
#pragma unroll
            for (int r = 0; r < 4; ++r) oacc[nt][r] = 0.0f;

        for (int jt = 0; jt <= jmax; ++jt) {
            const int cur = jt & 1;
            __syncthreads();

            // unguarded prefetch of tile jt+1 (over-read lands in live ws, discarded)
            const long pno = (long)((jt + 1)*64) * 512;
            s16x8 kreg = *(const s16x8*)(Kg + pno + (long)kr*512 + kc);
            s16x4 v0r  = *(const s16x4*)(Vg + pno + (long)vj*512 + vd);
            s16x4 v1r  = *(const s16x4*)(Vg + pno + (long)(vj+1)*512 + vd);
            const int mv = mg[jt*64 + lane];
            const unsigned long long bal = __ballot(mv == 0);

            f32x4 sacc[4];
#pragma unroll
            for (int ct = 0; ct < 4; ++ct) {
                s16x8 kf = *(const s16x8*)&sK[cur][(ct*16 + lcol)*LDK + g*8];
                sacc[ct] = __builtin_amdgcn_mfma_f32_16x16x32_bf16(
                    kf, qf[0], z4, 0, 0, 0);
            }
#pragma unroll
            for (int ct = 0; ct < 4; ++ct) {
                s16x8 kf = *(const s16x8*)&sK[cur][(ct*16 + lcol)*LDK + 32 + g*8];
                sacc[ct] = __builtin_amdgcn_mfma_f32_16x16x32_bf16(
                    kf, qf[1], sacc[ct], 0, 0, 0);
            }

            if (bal) {
#pragma unroll
                for (int ct = 0; ct < 4; ++ct) {
                    const unsigned nib = (unsigned)(bal >> (ct*16 + g*4)) & 15u;
#pragma unroll
                    for (int r = 0; r < 4; ++r)
                        if (nib & (1u << r)) sacc[ct][r] = -2.0e5f;
                }
            }
            if (jt >= 2*qt) {
                const int qrow = qt*128 + wid*16 + lcol;
#pragma unroll
                for (int ct = 0; ct < 4; ++ct) {
                    const int jb = jt*64 + ct*16 + g*4;
#pragma unroll
                    for (int r = 0; r < 4; ++r)
                        if (jb + r > qrow) sacc[ct][r] = -2.0e5f;
                }
            }

            // no-max softmax: Q pre-scaled by 0.125*log2e, so p = 2^s directly.
            // Pack P rows into registers: Wlo[ct] = (p0,p1), Whi[ct] = (p2,p3).
            unsigned Wlo[4], Whi[4];
            float ps = 0.0f;
#pragma unroll
            for (int ct = 0; ct < 4; ++ct) {
                const float p0 = __builtin_amdgcn_exp2f(sacc[ct][0]);
                const float p1 = __builtin_amdgcn_exp2f(sacc[ct][1]);
                const float p2 = __builtin_amdgcn_exp2f(sacc[ct][2]);
                const float p3 = __builtin_amdgcn_exp2f(sacc[ct][3]);
                ps += (p0 + p1) + (p2 + p3);
                Wlo[ct] = pkbf_fast(p0, p1);
                Whi[ct] = pkbf_fast(p2, p3);
            }
            lrl += ps;

            // PV with in-register P exchange (replaces the sPp LDS round-trip):
            // C = swap16(swap32(X,Y)).first -> pu words from writer w0=(2g)&3,
            // D = .second -> words from w1=(2g+1)&3; ct-selection by g>>1 falls
            // out of the 32-swap. Verified equal to the old myP read pattern.
#pragma unroll
            for (int ks = 0; ks < 2; ++ks) {
                unsigned c0 = Wlo[ks*2], d0 = Wlo[ks*2 + 1];
                unsigned c1 = Whi[ks*2], d1 = Whi[ks*2 + 1];
                pl_swap32(c0, d0); pl_swap16(c0, d0);
                pl_swap32(c1, d1); pl_swap16(c1, d1);
                u32x4 pu; pu.x = c0; pu.y = c1; pu.z = d0; pu.w = d1;
                const s16x8 pf = __builtin_bit_cast(s16x8, pu);
#pragma unroll
                for (int nt = 0; nt < 4; ++nt) {
                    s16x8 vf = *(const s16x8*)&sVt[cur][(nt*16 + lcol)*LDV + ks*32 + g*8];
                    oacc[nt] = __builtin_amdgcn_mfma_f32_16x16x32_bf16(
                        pf, vf, oacc[nt], 0, 0, 0);
                }
            }

            // stage next tile at iteration end (keeps V-reads ahead of these
            // in the in-order DS queue; the loop-top barrier drains them)
            if (jt < jmax) {
                const int nb = cur ^ 1;
                *(s16x8*)&sK[nb][kr*LDK + kc] = kreg;
                short* sv = (short*)sVt[nb];
#pragma unroll
                for (int i = 0; i < 4; ++i) {
                    s16x2 pr; pr.x = v0r[i]; pr.y = v1r[i];
                    *(s16x2*)&sv[(vd+i)*LDV + vj] = pr;
                }
            }
        }

        // epilogue: reduce row sums (only cross-lane step), normalize, store
        lrl += __shfl_xor(lrl, 16);
        lrl += __shfl_xor(lrl, 32);
        const float inv = 1.0f / lrl;
        float invr[4];
#pragma unroll
        for (int r = 0; r < 4; ++r)
            invr[r] = bpermf((g*4 + r) << 2, inv);

        __hip_bfloat16* Og = O + (long)(b*L_ + qt*128)*HID + h*DH;
#pragma unroll
        for (int r = 0; r < 4; ++r) {
            const int row = wid*16 + g*4 + r;
#pragma unroll
            for (int nt = 0; nt < 4; ++nt)
                Og[(long)row*HID + nt*16 + lcol] =
                    __float2bfloat16(oacc[nt][r] * invr[r]);
        }
    }
}

extern "C" void kernel_launch(void* const* d_in, const int* in_sizes, int n_in,
                              void* d_out, int out_size, void* d_ws, size_t ws_size,
                              hipStream_t stream) {
    const float* x   = (const float*)d_in[0];
    const int*   am  = (const int*)d_in[1];
    const float* q_w = (const float*)d_in[2];
    const float* q_b = (const float*)d_in[3];
    const float* k_w = (const float*)d_in[4];
    const float* k_b = (const float*)d_in[5];
    const float* v_w = (const float*)d_in[6];
    const float* v_b = (const float*)d_in[7];
    const float* o_w = (const float*)d_in[8];
    const float* o_b = (const float*)d_in[9];
    float* out = (float*)d_out;
    char* ws = (char*)d_ws;
    dim3 blk(256);
    const float qsc = 0.18033688011112042f;   // 0.125 * log2(e)

    if (ws_size >= 37748736) {
        __hip_bfloat16* Qb   = (__hip_bfloat16*)d_out;
        __hip_bfloat16* xb   = (__hip_bfloat16*)((char*)d_out + 16777216);
        __hip_bfloat16* wcat = (__hip_bfloat16*)(ws);
        __hip_bfloat16* qwb  = (__hip_bfloat16*)(ws);
        __hip_bfloat16* kwb  = (__hip_bfloat16*)(ws + 8388608);
        __hip_bfloat16* vwb  = (__hip_bfloat16*)(ws + 10485760);
        __hip_bfloat16* Kt   = (__hip_bfloat16*)(ws + 12582912);
        __hip_bfloat16* Vt   = (__hip_bfloat16*)(ws + 16777216);
        __hip_bfloat16* Ob   = (__hip_bfloat16*)(ws + 20971520);
        __hip_bfloat16* owb  = qwb;   // reuse after QKV GEMM (stream-ordered)

        cvt_xqkv<<<7168, blk, 0, stream>>>(x, q_w, k_w, v_w, xb, qwb, kwb, vwb);
        gemm_qkv<<<dim3(32, 24), blk, 0, stream>>>(xb, wcat, q_b, k_b, v_b, Qb, Kt, Vt);
        cvt8<<<2048, blk, 0, stream>>>(o_w, owb, 524288);
        gqa_flash<<<dim3(8, 64), dim3(512), 0, stream>>>(Qb, Kt, Vt, am, Ob);
        gemm_fast<float><<<dim3(32, 16), blk, 0, stream>>>(Ob, owb, o_b, out, 4096, 2048, 2048);
    } else {
        __hip_bfloat16* Qb = (__hip_bfloat16*)d_out;
        __hip_bfloat16* Kt = (__hip_bfloat16*)(ws);
        __hip_bfloat16* Vt = (__hip_bfloat16*)(ws + 4194304);
        __hip_bfloat16* Ob = (__hip_bfloat16*)(ws + 8388608);
        gemm_bt_bias<float, __hip_bfloat16><<<dim3(32,16), blk, 0, stream>>>(x, q_w, q_b, Qb, 4096, 2048, 2048, qsc);
        gemm_bt_bias<float, __hip_bfloat16><<<dim3(32, 4), blk, 0, stream>>>(x, k_w, k_b, Kt, 4096,  512, 2048, 1.0f);
        gemm_bt_bias<float, __hip_bfloat16><<<dim3(32, 4), blk, 0, stream>>>(x, v_w, v_b, Vt, 4096,  512, 2048, 1.0f);
        gqa_flash<<<dim3(8, 64), dim3(512), 0, stream>>>(Qb, Kt, Vt, am, Ob);
        gemm_bt_bias<__hip_bfloat16, float><<<dim3(32,16), blk, 0, stream>>>(Ob, o_w, o_b, out, 4096, 2048, 2048, 1.0f);
    }
}